// Round 2
// baseline (32.804 us; speedup 1.0000x reference)
//
#include <hip/hip_runtime.h>

#define NCLS   80
#define NBINS  16
#define T_TGT  64
#define B_IMG  32
#define N_TGT  (B_IMG * T_TGT)   // 2048
#define N_DFL  (3 * B_IMG)       // 96
#define N_WAVES (N_TGT + N_DFL)  // 2144
#define WAVES_PER_BLOCK 4
#define N_BLOCKS (N_WAVES / WAVES_PER_BLOCK)  // 536 exactly

// ws layout: [0]=cls accum (f32), [1]=box accum (f32), [2]=ticket counter (u32)
// zeroed each launch by a hipMemsetAsync node.
//
// One 64-lane wave per target (focal cls) + one wave per (layer,image) (DFL).
// Block reduces its 4 wave partials in LDS; one atomicAdd pair per block into
// device-coherent accumulators; last block (ticket) writes the 3 outputs.
__global__ __launch_bounds__(256) void detloss_fused(
    const float* __restrict__ feat0,
    const float* __restrict__ feat1,
    const float* __restrict__ feat2,
    const float* __restrict__ tgt_box,
    const int*   __restrict__ tgt_cls,
    const int*   __restrict__ tgt_layer,
    float* __restrict__ accum,
    float* __restrict__ out)
{
    const int wlocal = threadIdx.x >> 6;
    const int wave = blockIdx.x * WAVES_PER_BLOCK + wlocal;
    const int lane = threadIdx.x & 63;

    float val = 0.0f;       // this wave's partial (lane 0 holds it)
    int   is_cls = 0;

    if (wave < N_TGT) {
        // ---------------- focal classification loss: one wave per target ----
        is_cls = 1;
        const int b = wave >> 6;       // wave / T_TGT
        const int t = wave & 63;
        const int bt = b * T_TGT + t;
        const int li = tgt_layer[bt];  // target's own layer (mask == exact match)

        const float* feat; int H, W;
        if (li == 0)      { feat = feat0; H = 80; W = 80; }
        else if (li == 1) { feat = feat1; H = 40; W = 40; }
        else              { feat = feat2; H = 20; W = 20; }

        const float cx = tgt_box[bt * 4 + 0];
        const float cy = tgt_box[bt * 4 + 1];
        int fx = (int)(cx * (float)W); fx = min(max(fx, 0), W - 1);
        int fy = (int)(cy * (float)H); fy = min(max(fy, 0), H - 1);

        const int HW = H * W;
        const float* pix = feat + (size_t)b * 144 * HW + fy * W + fx;

        // class logits live in channels 64..143; channel stride = HW floats
        const float v0 = pix[(size_t)(64 + lane) * HW];
        const float v1 = (lane < 16) ? pix[(size_t)(128 + lane) * HW] : -INFINITY;

        // wave-wide max
        float m = fmaxf(v0, v1);
        #pragma unroll
        for (int off = 32; off >= 1; off >>= 1)
            m = fmaxf(m, __shfl_xor(m, off));

        // wave-wide sum of exp
        float s = expf(v0 - m) + ((lane < 16) ? expf(v1 - m) : 0.0f);
        #pragma unroll
        for (int off = 32; off >= 1; off >>= 1)
            s += __shfl_xor(s, off);

        // broadcast logit of the target class (tc is wave-uniform)
        const int tc = tgt_cls[bt];
        float sel;
        if (tc < 64) sel = __shfl(v0, tc);
        else         sel = __shfl(v1, tc - 64);

        const float ce = m + logf(s) - sel;     // -log_softmax[tc]
        const float pt = expf(-ce);
        const float om = 1.0f - pt;
        val = om * om * ce;
    } else {
        // ---------------- DFL box loss: one wave per (layer, image) ---------
        const int w2 = wave - N_TGT;   // 0..95, always valid (grid sized exactly)
        const int li = w2 >> 5;        // 0..2
        const int b  = w2 & 31;        // 0..31

        // find LAST target t in image b with tgt_layer == li
        const int my_layer = tgt_layer[b * T_TGT + lane];
        const unsigned long long msk = __ballot(my_layer == li);
        if (msk != 0ull) {
            const int last = 63 - __clzll(msk);
            const int bt = b * T_TGT + last;

            const float* feat; int H, W;
            if (li == 0)      { feat = feat0; H = 80; W = 80; }
            else if (li == 1) { feat = feat1; H = 40; W = 40; }
            else              { feat = feat2; H = 20; W = 20; }

            const float cx = tgt_box[bt * 4 + 0];
            const float cy = tgt_box[bt * 4 + 1];
            const float bw = tgt_box[bt * 4 + 2];
            const float bh = tgt_box[bt * 4 + 3];
            int fx = (int)(cx * (float)W); fx = min(max(fx, 0), W - 1);
            int fy = (int)(cy * (float)H); fy = min(max(fy, 0), H - 1);

            const int HW = H * W;
            const float* pix = feat + (size_t)b * 144 * HW + fy * W + fx;

            // dist logits: channels 0..63; lane l -> anchor a = l>>4, bin k = l&15
            const float v = pix[(size_t)lane * HW];
            const int a = lane >> 4;
            const int k = lane & 15;

            // per-16-lane-group (per-anchor) log-softmax via xor shuffles
            float gm = v;
            #pragma unroll
            for (int off = 8; off >= 1; off >>= 1)
                gm = fmaxf(gm, __shfl_xor(gm, off));
            float gs = expf(v - gm);
            #pragma unroll
            for (int off = 8; off >= 1; off >>= 1)
                gs += __shfl_xor(gs, off);
            const float lps = v - gm - logf(gs);    // log_softmax at bin k

            // target distance for this anchor: gt = {lw*W, lh*H, lw*W, lh*H}
            const float lw = fmaxf(bw, 0.0f) * 0.5f;
            const float lh = fmaxf(bh, 0.0f) * 0.5f;
            float ta = (a & 1) ? (lh * (float)H) : (lw * (float)W);
            ta = fminf(fmaxf(ta, 0.0f), (float)(NBINS - 1) - 1e-6f);
            const float lo = floorf(ta);
            const float wl = lo + 1.0f - ta;
            const float wr = ta - lo;
            const int lo_i = (int)lo;
            const int hi_i = min(lo_i + 1, NBINS - 1);

            float contrib = 0.0f;
            if (k == lo_i) contrib += -lps * wl;
            if (k == hi_i) contrib += -lps * wr;

            // sum across wave (covers all 4 anchors)
            #pragma unroll
            for (int off = 32; off >= 1; off >>= 1)
                contrib += __shfl_xor(contrib, off);
            val = contrib;
        }
    }

    // ---- block-level reduce of the 4 wave partials ----
    __shared__ float scls[WAVES_PER_BLOCK];
    __shared__ float sbox[WAVES_PER_BLOCK];
    if (lane == 0) {
        scls[wlocal] = is_cls ? val : 0.0f;
        sbox[wlocal] = is_cls ? 0.0f : val;
    }
    __syncthreads();

    if (threadIdx.x == 0) {
        float c = 0.0f, bx = 0.0f;
        #pragma unroll
        for (int i = 0; i < WAVES_PER_BLOCK; ++i) { c += scls[i]; bx += sbox[i]; }
        atomicAdd(&accum[0], c);   // device-coherent accumulation
        atomicAdd(&accum[1], bx);
        __threadfence();
        unsigned old = atomicAdd((unsigned*)&accum[2], 1u);
        if (old == (unsigned)(N_BLOCKS - 1)) {
            // all blocks' adds are ordered before their ticket increments:
            // coherent read-back via atomic RMW with identity
            const float cls_tot = atomicAdd(&accum[0], 0.0f);
            const float box_tot = atomicAdd(&accum[1], 0.0f);
            out[0] = cls_tot + box_tot;  // CLS_W = BOX_W = 1
            out[1] = cls_tot;
            out[2] = box_tot;
        }
    }
}

extern "C" void kernel_launch(void* const* d_in, const int* in_sizes, int n_in,
                              void* d_out, int out_size, void* d_ws, size_t ws_size,
                              hipStream_t stream) {
    const float* feat0     = (const float*)d_in[0];
    const float* feat1     = (const float*)d_in[1];
    const float* feat2     = (const float*)d_in[2];
    const float* tgt_box   = (const float*)d_in[3];
    const int*   tgt_cls   = (const int*)d_in[4];
    const int*   tgt_layer = (const int*)d_in[5];
    float* out = (float*)d_out;
    float* ws  = (float*)d_ws;

    // zero the 2 float accumulators + ticket counter (graph-legal memset node)
    hipMemsetAsync(ws, 0, 16, stream);

    detloss_fused<<<N_BLOCKS, 256, 0, stream>>>(feat0, feat1, feat2,
                                                tgt_box, tgt_cls, tgt_layer,
                                                ws, out);
}

// Round 3
// 19.378 us; speedup vs baseline: 1.6929x; 1.6929x over previous
//
#include <hip/hip_runtime.h>

#define NCLS   80
#define NBINS  16
#define T_TGT  64
#define B_IMG  32
#define N_TGT  (B_IMG * T_TGT)   // 2048 focal waves
#define N_DFL  (3 * B_IMG)       // 96 DFL waves
#define N_WAVES (N_TGT + N_DFL)  // 2144
#define WAVES_PER_BLOCK 8        // 512-thread blocks
#define N_BLOCKS (N_WAVES / WAVES_PER_BLOCK)  // 268 exactly

// ws layout: [0]=cls accum (f32), [1]=box accum (f32), [2]=ticket (u32)
// zeroed each launch by a 16-byte hipMemsetAsync node.
//
// One 64-lane wave per target (focal cls) + one wave per (layer,image) (DFL).
// Blocks 0..255 are pure-cls, 256..267 pure-DFL -> one guarded float atomic
// + one ticket atomic per block. Ordering WITHOUT __threadfence: the float
// atomicAdd RETURNS a value we consume, forcing s_waitcnt vmcnt(0) (RMW
// complete at the device coherent point) before the ticket atomic issues.
__global__ __launch_bounds__(512) void detloss_fused(
    const float* __restrict__ feat0,
    const float* __restrict__ feat1,
    const float* __restrict__ feat2,
    const float* __restrict__ tgt_box,
    const int*   __restrict__ tgt_cls,
    const int*   __restrict__ tgt_layer,
    float* __restrict__ accum,
    float* __restrict__ out)
{
    const int wlocal = threadIdx.x >> 6;
    const int wave = blockIdx.x * WAVES_PER_BLOCK + wlocal;
    const int lane = threadIdx.x & 63;

    float val = 0.0f;       // this wave's partial (held by lane 0)
    int   is_cls = 0;

    if (wave < N_TGT) {
        // ---------------- focal classification loss: one wave per target ----
        is_cls = 1;
        const int b = wave >> 6;       // wave / T_TGT
        const int t = wave & 63;
        const int bt = b * T_TGT + t;
        const int li = tgt_layer[bt];  // target's own layer (mask == exact match)

        const float* feat; int H, W;
        if (li == 0)      { feat = feat0; H = 80; W = 80; }
        else if (li == 1) { feat = feat1; H = 40; W = 40; }
        else              { feat = feat2; H = 20; W = 20; }

        const float cx = tgt_box[bt * 4 + 0];
        const float cy = tgt_box[bt * 4 + 1];
        int fx = (int)(cx * (float)W); fx = min(max(fx, 0), W - 1);
        int fy = (int)(cy * (float)H); fy = min(max(fy, 0), H - 1);

        const int HW = H * W;
        const float* pix = feat + (size_t)b * 144 * HW + fy * W + fx;

        // class logits: channels 64..143; channel stride = HW floats
        const float v0 = pix[(size_t)(64 + lane) * HW];
        const float v1 = (lane < 16) ? pix[(size_t)(128 + lane) * HW] : -INFINITY;

        // wave-wide max
        float m = fmaxf(v0, v1);
        #pragma unroll
        for (int off = 32; off >= 1; off >>= 1)
            m = fmaxf(m, __shfl_xor(m, off));

        // wave-wide sum of exp
        float s = expf(v0 - m) + ((lane < 16) ? expf(v1 - m) : 0.0f);
        #pragma unroll
        for (int off = 32; off >= 1; off >>= 1)
            s += __shfl_xor(s, off);

        // broadcast logit of the target class (tc is wave-uniform)
        const int tc = tgt_cls[bt];
        float sel;
        if (tc < 64) sel = __shfl(v0, tc);
        else         sel = __shfl(v1, tc - 64);

        const float ce = m + logf(s) - sel;     // -log_softmax[tc]
        const float pt = expf(-ce);
        const float om = 1.0f - pt;
        val = om * om * ce;
    } else {
        // ---------------- DFL box loss: one wave per (layer, image) ---------
        const int w2 = wave - N_TGT;   // 0..95 (grid sized exactly)
        const int li = w2 >> 5;        // 0..2
        const int b  = w2 & 31;        // 0..31

        // find LAST target t in image b with tgt_layer == li
        const int my_layer = tgt_layer[b * T_TGT + lane];
        const unsigned long long msk = __ballot(my_layer == li);
        if (msk != 0ull) {
            const int last = 63 - __clzll(msk);
            const int bt = b * T_TGT + last;

            const float* feat; int H, W;
            if (li == 0)      { feat = feat0; H = 80; W = 80; }
            else if (li == 1) { feat = feat1; H = 40; W = 40; }
            else              { feat = feat2; H = 20; W = 20; }

            const float cx = tgt_box[bt * 4 + 0];
            const float cy = tgt_box[bt * 4 + 1];
            const float bw = tgt_box[bt * 4 + 2];
            const float bh = tgt_box[bt * 4 + 3];
            int fx = (int)(cx * (float)W); fx = min(max(fx, 0), W - 1);
            int fy = (int)(cy * (float)H); fy = min(max(fy, 0), H - 1);

            const int HW = H * W;
            const float* pix = feat + (size_t)b * 144 * HW + fy * W + fx;

            // dist logits: channels 0..63; lane l -> anchor a=l>>4, bin k=l&15
            const float v = pix[(size_t)lane * HW];
            const int a = lane >> 4;
            const int k = lane & 15;

            // per-16-lane-group (per-anchor) log-softmax via xor shuffles
            float gm = v;
            #pragma unroll
            for (int off = 8; off >= 1; off >>= 1)
                gm = fmaxf(gm, __shfl_xor(gm, off));
            float gs = expf(v - gm);
            #pragma unroll
            for (int off = 8; off >= 1; off >>= 1)
                gs += __shfl_xor(gs, off);
            const float lps = v - gm - logf(gs);    // log_softmax at bin k

            // target distance: gt = {lw*W, lh*H, lw*W, lh*H}
            const float lw = fmaxf(bw, 0.0f) * 0.5f;
            const float lh = fmaxf(bh, 0.0f) * 0.5f;
            float ta = (a & 1) ? (lh * (float)H) : (lw * (float)W);
            ta = fminf(fmaxf(ta, 0.0f), (float)(NBINS - 1) - 1e-6f);
            const float lo = floorf(ta);
            const float wl = lo + 1.0f - ta;
            const float wr = ta - lo;
            const int lo_i = (int)lo;
            const int hi_i = min(lo_i + 1, NBINS - 1);

            float contrib = 0.0f;
            if (k == lo_i) contrib += -lps * wl;
            if (k == hi_i) contrib += -lps * wr;

            // sum across wave (covers all 4 anchors)
            #pragma unroll
            for (int off = 32; off >= 1; off >>= 1)
                contrib += __shfl_xor(contrib, off);
            val = contrib;
        }
    }

    // ---- block-level reduce of the 8 wave partials ----
    __shared__ float scls[WAVES_PER_BLOCK];
    __shared__ float sbox[WAVES_PER_BLOCK];
    if (lane == 0) {
        scls[wlocal] = is_cls ? val : 0.0f;
        sbox[wlocal] = is_cls ? 0.0f : val;
    }
    __syncthreads();

    if (threadIdx.x == 0) {
        float c = 0.0f, bx = 0.0f;
        #pragma unroll
        for (int i = 0; i < WAVES_PER_BLOCK; ++i) { c += scls[i]; bx += sbox[i]; }

        // guarded returning atomics (blocks are pure-cls or pure-box, so at
        // most one fires); consuming the return forces vmcnt(0) => RMW is
        // complete at the coherent point before the ticket atomic issues.
        float r = 0.0f;
        if (c  != 0.0f) r += atomicAdd(&accum[0], c);
        if (bx != 0.0f) r += atomicAdd(&accum[1], bx);
        asm volatile("" :: "v"(r));                       // keep return live
        asm volatile("s_waitcnt vmcnt(0)" ::: "memory");  // RMWs done

        unsigned old = atomicAdd((unsigned*)&accum[2], 1u);
        if (old == (unsigned)(N_BLOCKS - 1)) {
            // every block's adds completed before its ticket increment, and
            // we saw all tickets -> coherent-point reads give final sums.
            const float cls_tot = atomicAdd(&accum[0], 0.0f);
            const float box_tot = atomicAdd(&accum[1], 0.0f);
            out[0] = cls_tot + box_tot;  // CLS_W = BOX_W = 1
            out[1] = cls_tot;
            out[2] = box_tot;
        }
    }
}

extern "C" void kernel_launch(void* const* d_in, const int* in_sizes, int n_in,
                              void* d_out, int out_size, void* d_ws, size_t ws_size,
                              hipStream_t stream) {
    const float* feat0     = (const float*)d_in[0];
    const float* feat1     = (const float*)d_in[1];
    const float* feat2     = (const float*)d_in[2];
    const float* tgt_box   = (const float*)d_in[3];
    const int*   tgt_cls   = (const int*)d_in[4];
    const int*   tgt_layer = (const int*)d_in[5];
    float* out = (float*)d_out;
    float* ws  = (float*)d_ws;

    // zero the 2 float accumulators + ticket counter (graph-legal memset node)
    hipMemsetAsync(ws, 0, 16, stream);

    detloss_fused<<<N_BLOCKS, 512, 0, stream>>>(feat0, feat1, feat2,
                                                tgt_box, tgt_cls, tgt_layer,
                                                ws, out);
}

// Round 4
// 16.769 us; speedup vs baseline: 1.9562x; 1.1556x over previous
//
#include <hip/hip_runtime.h>

#define NBINS  16
#define T_TGT  64
#define B_IMG  32
#define N_TGT  2048              // cls tasks
#define N_DFL  96                // dfl tasks
#define TASKS_PER_WAVE 4
#define WAVES_PER_BLOCK 8        // 512-thread blocks
#define N_BLOCKS 67              // 536 waves * 4 tasks = 2144 exactly
#define SLOT_BASE 16             // float index in ws where block slots start
#define SLOT_STRIDE 32           // 128B per block -> no line contention

// ws layout: [2]=ticket (u32, zeroed by memset node each launch)
//            [SLOT_BASE + bid*32 + {0,1}] = block's {cls,box} partial
//
// One kernel. Waves 0..511 handle 4 cls targets each; waves 512..535 handle
// 4 DFL (layer,image) pairs each. Blocks publish partials via atomicExch to
// private slots (parallel, device-coherent), vmcnt(0), one ticket RMW; last
// block reads all slots with parallel atomic loads and writes the 3 outputs.
__global__ __launch_bounds__(512) void detloss_fused(
    const float* __restrict__ feat0,
    const float* __restrict__ feat1,
    const float* __restrict__ feat2,
    const float* __restrict__ tgt_box,
    const int*   __restrict__ tgt_cls,
    const int*   __restrict__ tgt_layer,
    float* __restrict__ ws,
    float* __restrict__ out)
{
    const int wlocal = threadIdx.x >> 6;
    const int lane   = threadIdx.x & 63;
    const int gw     = blockIdx.x * WAVES_PER_BLOCK + wlocal;   // 0..535

    float cls_val = 0.0f, box_val = 0.0f;

    if (gw < 512) {
        // ============ focal cls loss: 4 consecutive targets, same image ====
        const int base = gw * 4;            // task ids base..base+3
        const int b    = base >> 6;         // image: same for all 4 tasks

        // ---- phase A: all metadata loads (independent) ----
        int li[4], tc[4]; float cx[4], cy[4];
        #pragma unroll
        for (int k = 0; k < 4; ++k) {
            const int bt = base + k;
            li[k] = tgt_layer[bt];
            tc[k] = tgt_cls[bt];
            cx[k] = tgt_box[bt * 4 + 0];
            cy[k] = tgt_box[bt * 4 + 1];
        }

        // ---- phase B: all 8 feature gathers (independent) ----
        float v0[4], v1[4];
        #pragma unroll
        for (int k = 0; k < 4; ++k) {
            const float* feat; int H, W;
            if (li[k] == 0)      { feat = feat0; H = 80; W = 80; }
            else if (li[k] == 1) { feat = feat1; H = 40; W = 40; }
            else                 { feat = feat2; H = 20; W = 20; }
            int fx = (int)(cx[k] * (float)W); fx = min(max(fx, 0), W - 1);
            int fy = (int)(cy[k] * (float)H); fy = min(max(fy, 0), H - 1);
            const int HW = H * W;
            const float* pix = feat + (size_t)b * 144 * HW + fy * W + fx;
            v0[k] = pix[(size_t)(64 + lane) * HW];
            v1[k] = (lane < 16) ? pix[(size_t)(128 + lane) * HW] : -INFINITY;
        }

        // ---- phase C: 4 interleaved softmax/focal chains ----
        #pragma unroll
        for (int k = 0; k < 4; ++k) {
            float m = fmaxf(v0[k], v1[k]);
            #pragma unroll
            for (int off = 32; off >= 1; off >>= 1)
                m = fmaxf(m, __shfl_xor(m, off));
            float s = __expf(v0[k] - m) + ((lane < 16) ? __expf(v1[k] - m) : 0.0f);
            #pragma unroll
            for (int off = 32; off >= 1; off >>= 1)
                s += __shfl_xor(s, off);
            const float sel = (tc[k] < 64) ? __shfl(v0[k], tc[k])
                                           : __shfl(v1[k], tc[k] - 64);
            const float ce = m + __logf(s) - sel;   // -log_softmax[tc]
            const float pt = __expf(-ce);
            const float om = 1.0f - pt;
            cls_val += om * om * ce;
        }
    } else {
        // ============ DFL box loss: 4 (layer,image) pairs, same layer ======
        const int base = (gw - 512) * 4;    // dfl ids base..base+3, base%32<=28
        const int li   = base >> 5;         // layer: uniform for all 4 tasks
        const float* feat; int H, W;
        if (li == 0)      { feat = feat0; H = 80; W = 80; }
        else if (li == 1) { feat = feat1; H = 40; W = 40; }
        else              { feat = feat2; H = 20; W = 20; }
        const int HW = H * W;

        // ---- phase A: per-lane layer loads for the 4 images ----
        int myl[4];
        #pragma unroll
        for (int k = 0; k < 4; ++k)
            myl[k] = tgt_layer[((base + k) & 31) * T_TGT + lane];

        // ---- phase B: ballots -> last target; metadata loads ----
        int has[4], bt[4];
        #pragma unroll
        for (int k = 0; k < 4; ++k) {
            const unsigned long long msk = __ballot(myl[k] == li);
            has[k] = (msk != 0ull);
            const int last = has[k] ? (63 - __clzll(msk)) : 0;
            bt[k] = ((base + k) & 31) * T_TGT + last;
        }
        float cx[4], cy[4], bw[4], bh[4];
        #pragma unroll
        for (int k = 0; k < 4; ++k) {
            cx[k] = tgt_box[bt[k] * 4 + 0];
            cy[k] = tgt_box[bt[k] * 4 + 1];
            bw[k] = tgt_box[bt[k] * 4 + 2];
            bh[k] = tgt_box[bt[k] * 4 + 3];
        }

        // ---- phase C: 4 dist-logit gathers (independent) ----
        float v[4];
        #pragma unroll
        for (int k = 0; k < 4; ++k) {
            const int b = (base + k) & 31;
            int fx = (int)(cx[k] * (float)W); fx = min(max(fx, 0), W - 1);
            int fy = (int)(cy[k] * (float)H); fy = min(max(fy, 0), H - 1);
            const float* pix = feat + (size_t)b * 144 * HW + fy * W + fx;
            v[k] = pix[(size_t)lane * HW];   // channel = lane (0..63)
        }

        // ---- phase D: per-16-lane-group softmax + DFL ----
        const int a = lane >> 4;      // anchor 0..3
        const int kk = lane & 15;     // bin
        #pragma unroll
        for (int k = 0; k < 4; ++k) {
            float gm = v[k];
            #pragma unroll
            for (int off = 8; off >= 1; off >>= 1)
                gm = fmaxf(gm, __shfl_xor(gm, off));
            float gs = __expf(v[k] - gm);
            #pragma unroll
            for (int off = 8; off >= 1; off >>= 1)
                gs += __shfl_xor(gs, off);
            const float lps = v[k] - gm - __logf(gs);

            const float lw = fmaxf(bw[k], 0.0f) * 0.5f;
            const float lh = fmaxf(bh[k], 0.0f) * 0.5f;
            float ta = (a & 1) ? (lh * (float)H) : (lw * (float)W);
            ta = fminf(fmaxf(ta, 0.0f), (float)(NBINS - 1) - 1e-6f);
            const float lo = floorf(ta);
            const float wl = lo + 1.0f - ta;
            const float wr = ta - lo;
            const int lo_i = (int)lo;
            const int hi_i = min(lo_i + 1, NBINS - 1);

            float contrib = 0.0f;
            if (kk == lo_i) contrib += -lps * wl;
            if (kk == hi_i) contrib += -lps * wr;
            #pragma unroll
            for (int off = 32; off >= 1; off >>= 1)
                contrib += __shfl_xor(contrib, off);
            box_val += has[k] ? contrib : 0.0f;
        }
    }

    // ---- block reduce (8 wave partials; values are wave-uniform) ----
    __shared__ float scls[WAVES_PER_BLOCK];
    __shared__ float sbox[WAVES_PER_BLOCK];
    if (lane == 0) { scls[wlocal] = cls_val; sbox[wlocal] = box_val; }
    __syncthreads();

    if (wlocal == 0) {
        unsigned old = 0u;
        if (lane == 0) {
            float c = 0.0f, bx = 0.0f;
            #pragma unroll
            for (int i = 0; i < WAVES_PER_BLOCK; ++i) { c += scls[i]; bx += sbox[i]; }
            // publish to private line-padded slots (parallel device-scope RMW)
            float dummy = atomicExch(&ws[SLOT_BASE + blockIdx.x * SLOT_STRIDE], c);
            dummy += atomicExch(&ws[SLOT_BASE + blockIdx.x * SLOT_STRIDE + 1], bx);
            asm volatile("" :: "v"(dummy));                   // keep returns live
            asm volatile("s_waitcnt vmcnt(0)" ::: "memory");  // RMWs at coherent pt
            old = atomicAdd((unsigned*)ws + 2, 1u);           // ticket
        }
        const unsigned old_b = (unsigned)__shfl((int)old, 0);
        if (old_b == (unsigned)(N_BLOCKS - 1)) {
            // last block: coherent parallel reads of all 67 slot pairs
            float c2 = atomicAdd(&ws[SLOT_BASE + lane * SLOT_STRIDE], 0.0f);
            float b2 = atomicAdd(&ws[SLOT_BASE + lane * SLOT_STRIDE + 1], 0.0f);
            if (lane < N_BLOCKS - 64) {   // lanes 0..2 pick up slots 64..66
                c2 += atomicAdd(&ws[SLOT_BASE + (64 + lane) * SLOT_STRIDE], 0.0f);
                b2 += atomicAdd(&ws[SLOT_BASE + (64 + lane) * SLOT_STRIDE + 1], 0.0f);
            }
            #pragma unroll
            for (int off = 32; off >= 1; off >>= 1) {
                c2 += __shfl_xor(c2, off);
                b2 += __shfl_xor(b2, off);
            }
            if (lane == 0) {
                out[0] = c2 + b2;   // CLS_W = BOX_W = 1
                out[1] = c2;
                out[2] = b2;
            }
        }
    }
}

extern "C" void kernel_launch(void* const* d_in, const int* in_sizes, int n_in,
                              void* d_out, int out_size, void* d_ws, size_t ws_size,
                              hipStream_t stream) {
    const float* feat0     = (const float*)d_in[0];
    const float* feat1     = (const float*)d_in[1];
    const float* feat2     = (const float*)d_in[2];
    const float* tgt_box   = (const float*)d_in[3];
    const int*   tgt_cls   = (const int*)d_in[4];
    const int*   tgt_layer = (const int*)d_in[5];
    float* out = (float*)d_out;
    float* ws  = (float*)d_ws;

    // zero the ticket (graph-legal memset node)
    hipMemsetAsync(ws, 0, 16, stream);

    detloss_fused<<<N_BLOCKS, 512, 0, stream>>>(feat0, feat1, feat2,
                                                tgt_box, tgt_cls, tgt_layer,
                                                ws, out);
}

// Round 5
// 12.720 us; speedup vs baseline: 2.5790x; 1.3184x over previous
//
#include <hip/hip_runtime.h>

#define NBINS  16
#define T_TGT  64
#define B_IMG  32
#define N_TGT  2048              // cls tasks
#define N_DFL  96                // dfl tasks
#define WAVES_PER_BLOCK 8        // 512-thread blocks
#define N_BLOCKS 67              // 536 waves * 4 tasks/wave = 2144 tasks exactly
#define SLOT_BASE 16             // float index in ws where block slots start
#define SLOT_STRIDE 32           // 128B per block slot

// ws slot layout per block i (floats, at SLOT_BASE + i*SLOT_STRIDE):
//   +0 = cls partial, +1 = box partial, +2 = flag (u32)
//
// NO initialization required: publishers atomicExch data then flag=1 (poison
// is overwritten); the collector's atomicCAS(flag,1,0) consumes AND resets
// the flag, so every launch leaves flags at 0 for the next graph replay.
// => single kernel node, no memset node.
__global__ __launch_bounds__(512) void detloss_fused(
    const float* __restrict__ feat0,
    const float* __restrict__ feat1,
    const float* __restrict__ feat2,
    const float* __restrict__ tgt_box,
    const int*   __restrict__ tgt_cls,
    const int*   __restrict__ tgt_layer,
    float* __restrict__ ws,
    float* __restrict__ out)
{
    const int wlocal = threadIdx.x >> 6;
    const int lane   = threadIdx.x & 63;
    const int gw     = blockIdx.x * WAVES_PER_BLOCK + wlocal;   // 0..535

    float cls_val = 0.0f, box_val = 0.0f;

    if (gw < 512) {
        // ============ focal cls loss: 4 consecutive targets, same image ====
        const int base = gw * 4;            // task ids base..base+3
        const int b    = base >> 6;         // image: same for all 4 tasks

        // ---- phase A: all metadata loads (independent) ----
        int li[4], tc[4]; float cx[4], cy[4];
        #pragma unroll
        for (int k = 0; k < 4; ++k) {
            const int bt = base + k;
            li[k] = tgt_layer[bt];
            tc[k] = tgt_cls[bt];
            cx[k] = tgt_box[bt * 4 + 0];
            cy[k] = tgt_box[bt * 4 + 1];
        }

        // ---- phase B: all 8 feature gathers (independent) ----
        float v0[4], v1[4];
        #pragma unroll
        for (int k = 0; k < 4; ++k) {
            const float* feat; int H, W;
            if (li[k] == 0)      { feat = feat0; H = 80; W = 80; }
            else if (li[k] == 1) { feat = feat1; H = 40; W = 40; }
            else                 { feat = feat2; H = 20; W = 20; }
            int fx = (int)(cx[k] * (float)W); fx = min(max(fx, 0), W - 1);
            int fy = (int)(cy[k] * (float)H); fy = min(max(fy, 0), H - 1);
            const int HW = H * W;
            const float* pix = feat + (size_t)b * 144 * HW + fy * W + fx;
            v0[k] = pix[(size_t)(64 + lane) * HW];
            v1[k] = (lane < 16) ? pix[(size_t)(128 + lane) * HW] : -INFINITY;
        }

        // ---- phase C: 4 interleaved softmax/focal chains ----
        #pragma unroll
        for (int k = 0; k < 4; ++k) {
            float m = fmaxf(v0[k], v1[k]);
            #pragma unroll
            for (int off = 32; off >= 1; off >>= 1)
                m = fmaxf(m, __shfl_xor(m, off));
            float s = __expf(v0[k] - m) + ((lane < 16) ? __expf(v1[k] - m) : 0.0f);
            #pragma unroll
            for (int off = 32; off >= 1; off >>= 1)
                s += __shfl_xor(s, off);
            const float sel = (tc[k] < 64) ? __shfl(v0[k], tc[k])
                                           : __shfl(v1[k], tc[k] - 64);
            const float ce = m + __logf(s) - sel;   // -log_softmax[tc]
            const float pt = __expf(-ce);
            const float om = 1.0f - pt;
            cls_val += om * om * ce;
        }
    } else {
        // ============ DFL box loss: 4 (layer,image) pairs, same layer ======
        const int base = (gw - 512) * 4;    // dfl ids base..base+3
        const int li   = base >> 5;         // layer: uniform for all 4 tasks
        const float* feat; int H, W;
        if (li == 0)      { feat = feat0; H = 80; W = 80; }
        else if (li == 1) { feat = feat1; H = 40; W = 40; }
        else              { feat = feat2; H = 20; W = 20; }
        const int HW = H * W;

        // ---- phase A: per-lane layer loads for the 4 images ----
        int myl[4];
        #pragma unroll
        for (int k = 0; k < 4; ++k)
            myl[k] = tgt_layer[((base + k) & 31) * T_TGT + lane];

        // ---- phase B: ballots -> last target; metadata loads ----
        int has[4], bt[4];
        #pragma unroll
        for (int k = 0; k < 4; ++k) {
            const unsigned long long msk = __ballot(myl[k] == li);
            has[k] = (msk != 0ull);
            const int last = has[k] ? (63 - __clzll(msk)) : 0;
            bt[k] = ((base + k) & 31) * T_TGT + last;
        }
        float cx[4], cy[4], bw[4], bh[4];
        #pragma unroll
        for (int k = 0; k < 4; ++k) {
            cx[k] = tgt_box[bt[k] * 4 + 0];
            cy[k] = tgt_box[bt[k] * 4 + 1];
            bw[k] = tgt_box[bt[k] * 4 + 2];
            bh[k] = tgt_box[bt[k] * 4 + 3];
        }

        // ---- phase C: 4 dist-logit gathers (independent) ----
        float v[4];
        #pragma unroll
        for (int k = 0; k < 4; ++k) {
            const int b = (base + k) & 31;
            int fx = (int)(cx[k] * (float)W); fx = min(max(fx, 0), W - 1);
            int fy = (int)(cy[k] * (float)H); fy = min(max(fy, 0), H - 1);
            const float* pix = feat + (size_t)b * 144 * HW + fy * W + fx;
            v[k] = pix[(size_t)lane * HW];   // channel = lane (0..63)
        }

        // ---- phase D: per-16-lane-group softmax + DFL ----
        const int a = lane >> 4;      // anchor 0..3
        const int kk = lane & 15;     // bin
        #pragma unroll
        for (int k = 0; k < 4; ++k) {
            float gm = v[k];
            #pragma unroll
            for (int off = 8; off >= 1; off >>= 1)
                gm = fmaxf(gm, __shfl_xor(gm, off));
            float gs = __expf(v[k] - gm);
            #pragma unroll
            for (int off = 8; off >= 1; off >>= 1)
                gs += __shfl_xor(gs, off);
            const float lps = v[k] - gm - __logf(gs);

            const float lw = fmaxf(bw[k], 0.0f) * 0.5f;
            const float lh = fmaxf(bh[k], 0.0f) * 0.5f;
            float ta = (a & 1) ? (lh * (float)H) : (lw * (float)W);
            ta = fminf(fmaxf(ta, 0.0f), (float)(NBINS - 1) - 1e-6f);
            const float lo = floorf(ta);
            const float wl = lo + 1.0f - ta;
            const float wr = ta - lo;
            const int lo_i = (int)lo;
            const int hi_i = min(lo_i + 1, NBINS - 1);

            float contrib = 0.0f;
            if (kk == lo_i) contrib += -lps * wl;
            if (kk == hi_i) contrib += -lps * wr;
            #pragma unroll
            for (int off = 32; off >= 1; off >>= 1)
                contrib += __shfl_xor(contrib, off);
            box_val += has[k] ? contrib : 0.0f;
        }
    }

    // ---- block reduce (8 wave partials; values are wave-uniform) ----
    __shared__ float scls[WAVES_PER_BLOCK];
    __shared__ float sbox[WAVES_PER_BLOCK];
    if (lane == 0) { scls[wlocal] = cls_val; sbox[wlocal] = box_val; }
    __syncthreads();

    // ---- publish: data exch -> vmcnt(0) -> flag exch (overwrites poison) ---
    if (threadIdx.x == 0) {
        float c = 0.0f, bx = 0.0f;
        #pragma unroll
        for (int i = 0; i < WAVES_PER_BLOCK; ++i) { c += scls[i]; bx += sbox[i]; }
        float* slot = ws + SLOT_BASE + blockIdx.x * SLOT_STRIDE;
        float d0 = atomicExch(slot + 0, c);
        float d1 = atomicExch(slot + 1, bx);
        asm volatile("" :: "v"(d0), "v"(d1));             // keep returns live
        asm volatile("s_waitcnt vmcnt(0)" ::: "memory");  // data at coherent pt
        atomicExch((unsigned*)(slot + 2), 1u);            // flag := 1
    }

    // ---- collector: block 0 wave 0; CAS consumes AND resets each flag -----
    if (blockIdx.x == 0 && wlocal == 0) {
        float c2 = 0.0f, b2 = 0.0f;
        for (int f = lane; f < N_BLOCKS; f += 64) {
            float* slot = ws + SLOT_BASE + f * SLOT_STRIDE;
            unsigned* flg = (unsigned*)(slot + 2);
            while (atomicCAS(flg, 1u, 0u) != 1u)
                __builtin_amdgcn_s_sleep(1);
            c2 += atomicAdd(slot + 0, 0.0f);   // coherent-point reads
            b2 += atomicAdd(slot + 1, 0.0f);
        }
        #pragma unroll
        for (int off = 32; off >= 1; off >>= 1) {
            c2 += __shfl_xor(c2, off);
            b2 += __shfl_xor(b2, off);
        }
        if (lane == 0) {
            out[0] = c2 + b2;   // CLS_W = BOX_W = 1
            out[1] = c2;
            out[2] = b2;
        }
    }
}

extern "C" void kernel_launch(void* const* d_in, const int* in_sizes, int n_in,
                              void* d_out, int out_size, void* d_ws, size_t ws_size,
                              hipStream_t stream) {
    const float* feat0     = (const float*)d_in[0];
    const float* feat1     = (const float*)d_in[1];
    const float* feat2     = (const float*)d_in[2];
    const float* tgt_box   = (const float*)d_in[3];
    const int*   tgt_cls   = (const int*)d_in[4];
    const int*   tgt_layer = (const int*)d_in[5];
    float* out = (float*)d_out;
    float* ws  = (float*)d_ws;

    // single graph node: no memset, handshake is self-resetting & poison-proof
    detloss_fused<<<N_BLOCKS, 512, 0, stream>>>(feat0, feat1, feat2,
                                                tgt_box, tgt_cls, tgt_layer,
                                                ws, out);
}

// Round 6
// 11.098 us; speedup vs baseline: 2.9558x; 1.1461x over previous
//
#include <hip/hip_runtime.h>

#define NBINS  16
#define T_TGT  64
#define B_IMG  32
#define N_TGT  2048              // cls tasks
#define N_DFL  96                // dfl tasks
#define WAVES_PER_BLOCK 8        // 512-thread blocks
#define N_BLOCKS 67              // 536 waves * 4 tasks/wave = 2144 tasks exactly
#define SLOT_BASE 16             // float index in ws where block slots start
#define SLOT_STRIDE 32           // 128B per block slot

// ws slot layout per block i (floats, at SLOT_BASE + i*SLOT_STRIDE):
//   +0 = cls partial, +1 = box partial, +2 = flag (u32)
//
// NO initialization required: publishers atomicExch data then flag=1 (poison
// is overwritten); the collector's atomicCAS(flag,1,0) consumes AND resets
// the flag, so every launch leaves flags at 0 for the next graph replay.
// => single kernel node, no memset node.
//
// cls waves: 4 targets per wave, ONE PER 16-LANE GROUP (lane il=lane&15 holds
// 5 logits at channels 64+il+16*slot). Group softmax = 4 in-lane ops + 4 xor
// shuffle levels; all 4 targets reduce simultaneously -> 14 DS ops/wave
// instead of 52.
__global__ __launch_bounds__(512) void detloss_fused(
    const float* __restrict__ feat0,
    const float* __restrict__ feat1,
    const float* __restrict__ feat2,
    const float* __restrict__ tgt_box,
    const int*   __restrict__ tgt_cls,
    const int*   __restrict__ tgt_layer,
    float* __restrict__ ws,
    float* __restrict__ out)
{
    const int wlocal = threadIdx.x >> 6;
    const int lane   = threadIdx.x & 63;
    const int gw     = blockIdx.x * WAVES_PER_BLOCK + wlocal;   // 0..535

    float cls_val = 0.0f, box_val = 0.0f;

    if (gw < 512) {
        // ===== focal cls loss: 4 targets/wave, one per 16-lane group =======
        const int j  = lane >> 4;          // group = which of the 4 targets
        const int il = lane & 15;          // lane-in-group
        const int base = gw * 4;
        const int bt = base + j;           // this group's target
        const int b  = base >> 6;          // image (same for all 4 tasks)

        // metadata (redundant across the 16 lanes of a group; all parallel)
        const int li = tgt_layer[bt];
        const int tc = tgt_cls[bt];
        const float cx = tgt_box[bt * 4 + 0];
        const float cy = tgt_box[bt * 4 + 1];

        const float* feat; int H, W;
        if (li == 0)      { feat = feat0; H = 80; W = 80; }
        else if (li == 1) { feat = feat1; H = 40; W = 40; }
        else              { feat = feat2; H = 20; W = 20; }
        int fx = (int)(cx * (float)W); fx = min(max(fx, 0), W - 1);
        int fy = (int)(cy * (float)H); fy = min(max(fy, 0), H - 1);
        const int HW = H * W;
        const float* pix = feat + (size_t)b * 144 * HW + fy * W + fx;

        // 5 gathers: lane il holds logits for classes il+16*slot, slot=0..4
        float vv[5];
        #pragma unroll
        for (int s = 0; s < 5; ++s)
            vv[s] = pix[(size_t)(64 + il + 16 * s) * HW];

        // group max: 4 in-lane + 4 xor levels (1,2,4,8 stay inside group)
        float m = vv[0];
        #pragma unroll
        for (int s = 1; s < 5; ++s) m = fmaxf(m, vv[s]);
        #pragma unroll
        for (int off = 8; off >= 1; off >>= 1)
            m = fmaxf(m, __shfl_xor(m, off));

        // group sum of exp
        float s5 = 0.0f;
        #pragma unroll
        for (int s = 0; s < 5; ++s) s5 += __expf(vv[s] - m);
        #pragma unroll
        for (int off = 8; off >= 1; off >>= 1)
            s5 += __shfl_xor(s5, off);

        // the one lane holding the target-class logit computes the focal term
        float focal = 0.0f;
        if (il == (tc & 15)) {
            const int slot = tc >> 4;      // 0..4, constant-range select chain
            const float sel = (slot == 0) ? vv[0] :
                              (slot == 1) ? vv[1] :
                              (slot == 2) ? vv[2] :
                              (slot == 3) ? vv[3] : vv[4];
            const float ce = m + __logf(s5) - sel;   // -log_softmax[tc]
            const float pt = __expf(-ce);
            const float om = 1.0f - pt;
            focal = om * om * ce;
        }

        // wave total (sums the 4 selected lanes): 6-level butterfly
        #pragma unroll
        for (int off = 32; off >= 1; off >>= 1)
            focal += __shfl_xor(focal, off);
        cls_val = focal;
    } else {
        // ============ DFL box loss: 4 (layer,image) pairs, same layer ======
        const int base = (gw - 512) * 4;    // dfl ids base..base+3
        const int li   = base >> 5;         // layer: uniform for all 4 tasks
        const float* feat; int H, W;
        if (li == 0)      { feat = feat0; H = 80; W = 80; }
        else if (li == 1) { feat = feat1; H = 40; W = 40; }
        else              { feat = feat2; H = 20; W = 20; }
        const int HW = H * W;

        // ---- phase A: per-lane layer loads for the 4 images ----
        int myl[4];
        #pragma unroll
        for (int k = 0; k < 4; ++k)
            myl[k] = tgt_layer[((base + k) & 31) * T_TGT + lane];

        // ---- phase B: ballots -> last target; metadata loads ----
        int has[4], bt[4];
        #pragma unroll
        for (int k = 0; k < 4; ++k) {
            const unsigned long long msk = __ballot(myl[k] == li);
            has[k] = (msk != 0ull);
            const int last = has[k] ? (63 - __clzll(msk)) : 0;
            bt[k] = ((base + k) & 31) * T_TGT + last;
        }
        float cx[4], cy[4], bw[4], bh[4];
        #pragma unroll
        for (int k = 0; k < 4; ++k) {
            cx[k] = tgt_box[bt[k] * 4 + 0];
            cy[k] = tgt_box[bt[k] * 4 + 1];
            bw[k] = tgt_box[bt[k] * 4 + 2];
            bh[k] = tgt_box[bt[k] * 4 + 3];
        }

        // ---- phase C: 4 dist-logit gathers (independent) ----
        float v[4];
        #pragma unroll
        for (int k = 0; k < 4; ++k) {
            const int b = (base + k) & 31;
            int fx = (int)(cx[k] * (float)W); fx = min(max(fx, 0), W - 1);
            int fy = (int)(cy[k] * (float)H); fy = min(max(fy, 0), H - 1);
            const float* pix = feat + (size_t)b * 144 * HW + fy * W + fx;
            v[k] = pix[(size_t)lane * HW];   // channel = lane (0..63)
        }

        // ---- phase D: per-16-lane-group softmax + DFL ----
        const int a = lane >> 4;      // anchor 0..3
        const int kk = lane & 15;     // bin
        #pragma unroll
        for (int k = 0; k < 4; ++k) {
            float gm = v[k];
            #pragma unroll
            for (int off = 8; off >= 1; off >>= 1)
                gm = fmaxf(gm, __shfl_xor(gm, off));
            float gs = __expf(v[k] - gm);
            #pragma unroll
            for (int off = 8; off >= 1; off >>= 1)
                gs += __shfl_xor(gs, off);
            const float lps = v[k] - gm - __logf(gs);

            const float lw = fmaxf(bw[k], 0.0f) * 0.5f;
            const float lh = fmaxf(bh[k], 0.0f) * 0.5f;
            float ta = (a & 1) ? (lh * (float)H) : (lw * (float)W);
            ta = fminf(fmaxf(ta, 0.0f), (float)(NBINS - 1) - 1e-6f);
            const float lo = floorf(ta);
            const float wl = lo + 1.0f - ta;
            const float wr = ta - lo;
            const int lo_i = (int)lo;
            const int hi_i = min(lo_i + 1, NBINS - 1);

            float contrib = 0.0f;
            if (kk == lo_i) contrib += -lps * wl;
            if (kk == hi_i) contrib += -lps * wr;
            #pragma unroll
            for (int off = 32; off >= 1; off >>= 1)
                contrib += __shfl_xor(contrib, off);
            box_val += has[k] ? contrib : 0.0f;
        }
    }

    // ---- block reduce (8 wave partials; values are wave-uniform) ----
    __shared__ float scls[WAVES_PER_BLOCK];
    __shared__ float sbox[WAVES_PER_BLOCK];
    if (lane == 0) { scls[wlocal] = cls_val; sbox[wlocal] = box_val; }
    __syncthreads();

    // ---- publish: data exch -> vmcnt(0) -> flag exch (overwrites poison) ---
    if (threadIdx.x == 0) {
        float c = 0.0f, bx = 0.0f;
        #pragma unroll
        for (int i = 0; i < WAVES_PER_BLOCK; ++i) { c += scls[i]; bx += sbox[i]; }
        float* slot = ws + SLOT_BASE + blockIdx.x * SLOT_STRIDE;
        float d0 = atomicExch(slot + 0, c);
        float d1 = atomicExch(slot + 1, bx);
        asm volatile("" :: "v"(d0), "v"(d1));             // keep returns live
        asm volatile("s_waitcnt vmcnt(0)" ::: "memory");  // data at coherent pt
        atomicExch((unsigned*)(slot + 2), 1u);            // flag := 1
    }

    // ---- collector: block 0 wave 0; CAS consumes AND resets each flag -----
    if (blockIdx.x == 0 && wlocal == 0) {
        float c2 = 0.0f, b2 = 0.0f;
        for (int f = lane; f < N_BLOCKS; f += 64) {
            float* slot = ws + SLOT_BASE + f * SLOT_STRIDE;
            unsigned* flg = (unsigned*)(slot + 2);
            while (atomicCAS(flg, 1u, 0u) != 1u)
                __builtin_amdgcn_s_sleep(1);
            c2 += atomicAdd(slot + 0, 0.0f);   // coherent-point reads
            b2 += atomicAdd(slot + 1, 0.0f);
        }
        #pragma unroll
        for (int off = 32; off >= 1; off >>= 1) {
            c2 += __shfl_xor(c2, off);
            b2 += __shfl_xor(b2, off);
        }
        if (lane == 0) {
            out[0] = c2 + b2;   // CLS_W = BOX_W = 1
            out[1] = c2;
            out[2] = b2;
        }
    }
}

extern "C" void kernel_launch(void* const* d_in, const int* in_sizes, int n_in,
                              void* d_out, int out_size, void* d_ws, size_t ws_size,
                              hipStream_t stream) {
    const float* feat0     = (const float*)d_in[0];
    const float* feat1     = (const float*)d_in[1];
    const float* feat2     = (const float*)d_in[2];
    const float* tgt_box   = (const float*)d_in[3];
    const int*   tgt_cls   = (const int*)d_in[4];
    const int*   tgt_layer = (const int*)d_in[5];
    float* out = (float*)d_out;
    float* ws  = (float*)d_ws;

    // single graph node: no memset, handshake is self-resetting & poison-proof
    detloss_fused<<<N_BLOCKS, 512, 0, stream>>>(feat0, feat1, feat2,
                                                tgt_box, tgt_cls, tgt_layer,
                                                ws, out);
}